// Round 11
// baseline (212.021 us; speedup 1.0000x reference)
//
#include <hip/hip_runtime.h>

// Problem constants
#define TT 2048
#define DD 1024
#define NH 16
#define DH 64
#define MR 4096            // B*T rows

typedef __attribute__((ext_vector_type(8))) short bf16x8;
typedef __attribute__((ext_vector_type(4))) short bf16x4;
typedef __attribute__((ext_vector_type(4))) float f32x4;
typedef __attribute__((ext_vector_type(2))) unsigned int u32x2;

__device__ __forceinline__ float bf2f(unsigned short u) {
  unsigned int x = ((unsigned int)u) << 16;
  return __builtin_bit_cast(float, x);
}
__device__ __forceinline__ unsigned short f2bf(float f) {
  unsigned int x = __builtin_bit_cast(unsigned int, f);
  x = (x + 0x7fffu + ((x >> 16) & 1u)) >> 16;
  return (unsigned short)x;
}
__device__ __forceinline__ unsigned int pack_bf2(float a, float b) {
#if __has_builtin(__builtin_amdgcn_cvt_pk_bf16_f32)
  typedef __attribute__((ext_vector_type(2))) __bf16 bf2_t;
  bf2_t v = __builtin_amdgcn_cvt_pk_bf16_f32(a, b);
  return __builtin_bit_cast(unsigned int, v);
#else
  return (unsigned int)f2bf(a) | ((unsigned int)f2bf(b) << 16);
#endif
}
__device__ __forceinline__ bf16x8 load8(const float* p) {
  bf16x8 r;
#pragma unroll
  for (int e = 0; e < 8; ++e) r[e] = (short)f2bf(p[e]);
  return r;
}

#if __has_builtin(__builtin_amdgcn_mfma_f32_16x16x16_bf16)
#define MFMA_K16(A, B, C) __builtin_amdgcn_mfma_f32_16x16x16_bf16(A, B, C, 0, 0, 0)
#else
#define MFMA_K16(A, B, C) __builtin_amdgcn_mfma_f32_16x16x16bf16_1k(A, B, C, 0, 0, 0)
#endif

// Async global->LDS 16B/lane; LDS base wave-uniform, HW adds lane*16.
__device__ __forceinline__ void stage16(const unsigned short* g,
                                        unsigned short* lbase, int lane) {
#if __has_builtin(__builtin_amdgcn_global_load_lds)
  __builtin_amdgcn_global_load_lds(
      (const __attribute__((address_space(1))) unsigned int*)g,
      (__attribute__((address_space(3))) unsigned int*)(lbase + lane * 8),
      16, 0, 0);
#else
  *(bf16x8*)(lbase + lane * 8) = *(const bf16x8*)g;
#endif
}

// ---------------------------------------------------------------------------
// Convert: Wb rows = [Wk; Wq; Wv; Wo] (reference Q/K swap!); blocks >= 2048
// additionally convert x -> xb (linear).
// ---------------------------------------------------------------------------
__global__ __launch_bounds__(256) void cvt_all(
    const float* __restrict__ Wq, const float* __restrict__ Wk,
    const float* __restrict__ Wv, const float* __restrict__ Wo,
    const float* __restrict__ x,
    unsigned short* __restrict__ Wb, unsigned short* __restrict__ xb)
{
  int c = blockIdx.x * 256 + threadIdx.x;     // chunk of 8 elems
  if (c < 524288) {
    int idx = c * 8, n = idx >> 10, col = idx & 1023;
    const float* src = (n < 1024) ? Wk + (size_t)n * 1024
                     : (n < 2048) ? Wq + (size_t)(n - 1024) * 1024
                     : (n < 3072) ? Wv + (size_t)(n - 2048) * 1024
                                  : Wo + (size_t)(n - 3072) * 1024;
    *(bf16x8*)&Wb[idx] = load8(src + col);
  } else {
    size_t idx = (size_t)(c - 524288) * 8;
    *(bf16x8*)&xb[idx] = load8(&x[idx]);
  }
}

// ---------------------------------------------------------------------------
// Fused QKV projection (unchanged from R9/R10).
// ---------------------------------------------------------------------------
template <bool FAST>
__global__ __launch_bounds__(256) void gemm_qkv(
    const float* __restrict__ x, const unsigned short* __restrict__ xb,
    const unsigned short* __restrict__ Wb,
    unsigned short* __restrict__ Q, unsigned short* __restrict__ Kb,
    unsigned short* __restrict__ Vt)
{
  __shared__ unsigned short pool[8704];      // As(4096)+Bs(4096) | Tt(8704)
  unsigned short* As = pool;
  unsigned short* Bs = pool + 4096;

  const int tid = threadIdx.x, wave = tid >> 6, lane = tid & 63;
  const int lr = lane & 15, quad = lane >> 4;
  const int bm = blockIdx.x * 128, bn = blockIdx.y * 128;
  const int wm = (wave >> 1) * 64, wn = (wave & 1) * 64;

  f32x4 acc[4][4] = {};

  for (int k0 = 0; k0 < 1024; k0 += 32) {
#pragma unroll
    for (int i = 0; i < 2; ++i) {
      int c = wave * 128 + i * 64 + lane;    // chunk 0..511
      int row = c >> 2, l8 = (c & 3) ^ ((row >> 1) & 3);
      stage16(&Wb[(size_t)(bn + row) * 1024 + k0 + l8 * 8],
              &Bs[(wave * 2 + i) * 512], lane);
      if constexpr (FAST)
        stage16(&xb[(size_t)(bm + row) * 1024 + k0 + l8 * 8],
                &As[(wave * 2 + i) * 512], lane);
    }
    if constexpr (!FAST) {
#pragma unroll
      for (int i = 0; i < 2; ++i) {
        int c = tid + i * 256;
        int row = c >> 2, l8 = c & 3, p8 = l8 ^ ((row >> 1) & 3);
        *(bf16x8*)&As[row * 32 + p8 * 8] =
            load8(&x[(size_t)(bm + row) * 1024 + k0 + l8 * 8]);
      }
    }
    __syncthreads();

    bf16x8 af[4], bf[4];
#pragma unroll
    for (int mt = 0; mt < 4; ++mt) {
      int row = wm + mt * 16 + lr;
      af[mt] = *(const bf16x8*)&As[row * 32 + (quad ^ ((row >> 1) & 3)) * 8];
    }
#pragma unroll
    for (int nt = 0; nt < 4; ++nt) {
      int row = wn + nt * 16 + lr;
      bf[nt] = *(const bf16x8*)&Bs[row * 32 + (quad ^ ((row >> 1) & 3)) * 8];
    }
#pragma unroll
    for (int mt = 0; mt < 4; ++mt)
#pragma unroll
      for (int nt = 0; nt < 4; ++nt)
        acc[mt][nt] = __builtin_amdgcn_mfma_f32_16x16x32_bf16(
            af[mt], bf[nt], acc[mt][nt], 0, 0, 0);
    __syncthreads();
  }

  if (bn < 2048) {
    unsigned short* Cp = (bn < 1024) ? Q : Kb;
    int coff = (bn < 1024) ? bn : bn - 1024;
#pragma unroll
    for (int nt = 0; nt < 4; ++nt) {
      int col = coff + wn + nt * 16 + lr;
#pragma unroll
      for (int mt = 0; mt < 4; ++mt) {
        int row = bm + wm + mt * 16 + quad * 4;
#pragma unroll
        for (int r = 0; r < 4; ++r)
          Cp[(size_t)(row + r) * 1024 + col] = f2bf(acc[mt][nt][r]);
      }
    }
  } else {
    const int b = bm >> 11, t0 = bm & 2047, d0 = bn - 2048;
    unsigned short* Tt = pool;               // [64][136]
#pragma unroll
    for (int hv = 0; hv < 2; ++hv) {
      __syncthreads();
      if ((wave & 1) == hv) {
#pragma unroll
        for (int nt = 0; nt < 4; ++nt)
#pragma unroll
          for (int mt = 0; mt < 4; ++mt)
#pragma unroll
            for (int r = 0; r < 4; ++r)
              Tt[(nt * 16 + lr) * 136 + wm + mt * 16 + quad * 4 + r] =
                  f2bf(acc[mt][nt][r]);
      }
      __syncthreads();
#pragma unroll
      for (int ch = 0; ch < 4; ++ch) {
        int cc = tid + ch * 256;
        int d64 = cc >> 4, t8 = cc & 15;
        int dg = d0 + hv * 64 + d64;
        int h = dg >> 6, d = dg & 63;
        bf16x8 v = *(const bf16x8*)&Tt[d64 * 136 + t8 * 8];
        *(bf16x8*)&Vt[(((size_t)(b * NH + h) * 64 + d) << 11) + t0 + t8 * 8] = v;
      }
    }
  }
}

// ---------------------------------------------------------------------------
// Flash attention v5: dual q-group (32 q-rows/wave, 128-row Q-tile/block)
// + double-buffered async staging (prefetch j+1 overlapped with compute j).
// K/V fragments read from LDS ONCE per (nt,dt) feed BOTH q-groups' MFMAs:
// LDS reads and glds writes per q-row are halved vs R10 (the LDS pipe was
// the saturated resource: ~62 conflict-cyc per global_load_lds is structural).
// 256 blocks (pair p<->15-p, uniform 17 iters), 1 block/CU.
// ---------------------------------------------------------------------------
__global__ __launch_bounds__(256, 1) void attn(
    const unsigned short* __restrict__ Q,
    const unsigned short* __restrict__ Kb,
    const unsigned short* __restrict__ Vt,
    unsigned short* __restrict__ ctx)
{
  __shared__ unsigned short Ks[2 * 128 * 64];   // dbuf [kseq][d]
  __shared__ unsigned short Vs[2 * 64 * 128];   // dbuf [d][t]

  const int tid = threadIdx.x, wave = tid >> 6, lane = tid & 63;
  const int lr = lane & 15, quad = lane >> 4;
  const int p = blockIdx.x & 7;            // 8 pairs of 128-row q-tiles
  const int h = (blockIdx.x >> 3) & 15;
  const int b = blockIdx.x >> 7;

  const size_t qkbase = ((size_t)b * TT) * 1024 + h * 64;
  const size_t vbase  = ((size_t)(b * NH + h) * 64) << 11;
  const float QS = 0.125f * 1.44269504f;   // scale * log2(e)

  bf16x4 ones;
#pragma unroll
  for (int e = 0; e < 4; ++e) ones[e] = (short)0x3F80;   // bf16 1.0

  // staging helper: tile j -> buffer half bf
  auto stage_kv = [&](int j, int bf) {
#pragma unroll
    for (int i = 0; i < 4; ++i) {
      int ci = (wave * 4 + i) * 64 + lane;          // chunk 0..1023
      int row = ci >> 3, lc = (ci & 7) ^ (row & 7);
      stage16(&Kb[qkbase + (size_t)(j * 128 + row) * 1024 + lc * 8],
              &Ks[bf * 8192 + (wave * 4 + i) * 512], lane);
    }
#pragma unroll
    for (int i = 0; i < 4; ++i) {
      int ci = (wave * 4 + i) * 64 + lane;
      int d = ci >> 4, lc = (ci & 15) ^ (d & 15);
      stage16(&Vt[vbase + ((size_t)d << 11) + j * 128 + lc * 8],
              &Vs[bf * 8192 + (wave * 4 + i) * 512], lane);
    }
  };

#pragma unroll
  for (int pass = 0; pass < 2; ++pass) {
    const int qt = pass ? p : (15 - p);            // 128-row tile index
    const int q0 = qt * 128 + wave * 16;           // group-0 row base
    const int jmax = qt;

    // Q fragments for both groups, pre-scaled
    bf16x8 qf[2][2];
#pragma unroll
    for (int g = 0; g < 2; ++g)
#pragma unroll
      for (int kb = 0; kb < 2; ++kb) {
        bf16x8 raw = *(const bf16x8*)&Q[qkbase +
            (size_t)(q0 + g * 64 + lr) * 1024 + kb * 32 + quad * 8];
#pragma unroll
        for (int e = 0; e < 8; ++e)
          qf[g][kb][e] = (short)f2bf(bf2f((unsigned short)raw[e]) * QS);
      }

    float m_i[2] = {-1e30f, -1e30f};
    f32x4 od[2][4] = {};
    f32x4 ol[2] = {};

    stage_kv(0, 0);
    __syncthreads();

    for (int j = 0; j <= jmax; ++j) {
      const int buf = j & 1;
      if (j < jmax) stage_kv(j + 1, buf ^ 1);      // prefetch, drained by the
                                                   // end-of-iter barrier
      const bool diag = (j == jmax);

      // S^T for both groups; kf read ONCE per (nt,kb)
      f32x4 s[2][8];
#pragma unroll
      for (int nt = 0; nt < 8; ++nt) {
        f32x4 a0 = {0.f, 0.f, 0.f, 0.f}, a1 = a0;
        const bool need0 = !diag || nt < 4;        // diag: g0 cols>=64 all masked
#pragma unroll
        for (int kb = 0; kb < 2; ++kb) {
          int pc = (kb * 4 + quad) ^ (lr & 7);
          bf16x8 kf = *(const bf16x8*)&Ks[buf * 8192 + (nt * 16 + lr) * 64 + pc * 8];
          if (need0)
            a0 = __builtin_amdgcn_mfma_f32_16x16x32_bf16(kf, qf[0][kb], a0, 0, 0, 0);
          a1 = __builtin_amdgcn_mfma_f32_16x16x32_bf16(kf, qf[1][kb], a1, 0, 0, 0);
        }
        s[0][nt] = a0; s[1][nt] = a1;
      }

      // per-group: mask, softmax, pack P, rescale O/l
      bf16x4 pk[2][8];
      float alpha[2];
#pragma unroll
      for (int g = 0; g < 2; ++g) {
        const int nlim = (diag && g == 0) ? 4 : 8;
        const int qrow = q0 + g * 64 + lr;
        if (diag) {
#pragma unroll
          for (int nt = 0; nt < 8; ++nt)
            if (nt < nlim)
#pragma unroll
              for (int r = 0; r < 4; ++r) {
                int kpos = j * 128 + nt * 16 + quad * 4 + r;
                if (kpos > qrow) s[g][nt][r] = -1e30f;
              }
        }
        float mloc = -1e30f;
#pragma unroll
        for (int nt = 0; nt < 8; ++nt)
          if (nt < nlim)
#pragma unroll
            for (int r = 0; r < 4; ++r) mloc = fmaxf(mloc, s[g][nt][r]);
        mloc = fmaxf(mloc, __shfl_xor(mloc, 16, 64));
        mloc = fmaxf(mloc, __shfl_xor(mloc, 32, 64));
        float mnew = fmaxf(m_i[g], mloc);
        alpha[g] = exp2f(m_i[g] - mnew);
        m_i[g] = mnew;
#pragma unroll
        for (int nt = 0; nt < 8; ++nt)
          if (nt < nlim) {
            float p0 = exp2f(s[g][nt][0] - mnew), p1 = exp2f(s[g][nt][1] - mnew);
            float p2 = exp2f(s[g][nt][2] - mnew), p3 = exp2f(s[g][nt][3] - mnew);
            u32x2 u = {pack_bf2(p0, p1), pack_bf2(p2, p3)};
            pk[g][nt] = __builtin_bit_cast(bf16x4, u);
          }
        float am[4];
#pragma unroll
        for (int r = 0; r < 4; ++r) am[r] = __shfl(alpha[g], quad * 4 + r, 16);
#pragma unroll
        for (int dt = 0; dt < 4; ++dt)
#pragma unroll
          for (int r = 0; r < 4; ++r) od[g][dt][r] *= am[r];
#pragma unroll
        for (int r = 0; r < 4; ++r) ol[g][r] *= am[r];
      }

      // O += P·V, l += P·1 ; vf read ONCE per (nt,dt) for both groups
#pragma unroll
      for (int nt = 0; nt < 8; ++nt) {
        const bool need0 = !diag || nt < 4;
#pragma unroll
        for (int dt = 0; dt < 4; ++dt) {
          int pc = (nt * 2 + (quad >> 1)) ^ lr;
          bf16x4 vf = *(const bf16x4*)&Vs[buf * 8192 +
              (dt * 16 + lr) * 128 + pc * 8 + (quad & 1) * 4];
          if (need0) od[0][dt] = MFMA_K16(pk[0][nt], vf, od[0][dt]);
          od[1][dt] = MFMA_K16(pk[1][nt], vf, od[1][dt]);
        }
        if (need0) ol[0] = MFMA_K16(pk[0][nt], ones, ol[0]);
        ol[1] = MFMA_K16(pk[1][nt], ones, ol[1]);
      }
      __syncthreads();   // closes reads of buf, drains prefetch into buf^1
    }

    // epilogue both groups: O / l (ones-output broadcasts l to all lanes)
#pragma unroll
    for (int g = 0; g < 2; ++g)
#pragma unroll
      for (int dt = 0; dt < 4; ++dt) {
        int col = h * 64 + dt * 16 + lr;
#pragma unroll
        for (int r = 0; r < 4; ++r) {
          int row = q0 + g * 64 + quad * 4 + r;
          ctx[((size_t)b * TT + row) * 1024 + col] = f2bf(od[g][dt][r] / ol[g][r]);
        }
      }
  }
}

// ---------------------------------------------------------------------------
// Output projection: ctx(bf16) · Wo(bf16)^T + bo -> fp32 out (unchanged).
// ---------------------------------------------------------------------------
__global__ __launch_bounds__(256) void gemm_out(
    const unsigned short* __restrict__ A,
    const unsigned short* __restrict__ Bw,
    const float* __restrict__ bias,
    float* __restrict__ out)
{
  __shared__ unsigned short pool[8192];
  unsigned short* As = pool;
  unsigned short* Bs = pool + 4096;

  const int tid = threadIdx.x, wave = tid >> 6, lane = tid & 63;
  const int lr = lane & 15, quad = lane >> 4;
  const int bm = blockIdx.x * 128, bn = blockIdx.y * 128;
  const int wm = (wave >> 1) * 64, wn = (wave & 1) * 64;

  f32x4 acc[4][4] = {};

  for (int k0 = 0; k0 < 1024; k0 += 32) {
#pragma unroll
    for (int i = 0; i < 2; ++i) {
      int c = wave * 128 + i * 64 + lane;
      int row = c >> 2, l8 = (c & 3) ^ ((row >> 1) & 3);
      stage16(&A[(size_t)(bm + row) * 1024 + k0 + l8 * 8],
              &As[(wave * 2 + i) * 512], lane);
      stage16(&Bw[(size_t)(bn + row) * 1024 + k0 + l8 * 8],
              &Bs[(wave * 2 + i) * 512], lane);
    }
    __syncthreads();

    bf16x8 af[4], bf[4];
#pragma unroll
    for (int mt = 0; mt < 4; ++mt) {
      int row = wm + mt * 16 + lr;
      af[mt] = *(const bf16x8*)&As[row * 32 + (quad ^ ((row >> 1) & 3)) * 8];
    }
#pragma unroll
    for (int nt = 0; nt < 4; ++nt) {
      int row = wn + nt * 16 + lr;
      bf[nt] = *(const bf16x8*)&Bs[row * 32 + (quad ^ ((row >> 1) & 3)) * 8];
    }
#pragma unroll
    for (int mt = 0; mt < 4; ++mt)
#pragma unroll
      for (int nt = 0; nt < 4; ++nt)
        acc[mt][nt] = __builtin_amdgcn_mfma_f32_16x16x32_bf16(
            af[mt], bf[nt], acc[mt][nt], 0, 0, 0);
    __syncthreads();
  }

#pragma unroll
  for (int nt = 0; nt < 4; ++nt) {
    int col = bn + wn + nt * 16 + lr;
    float bv = bias[col];
#pragma unroll
    for (int mt = 0; mt < 4; ++mt) {
      int row = bm + wm + mt * 16 + quad * 4;
#pragma unroll
      for (int r = 0; r < 4; ++r)
        out[(size_t)(row + r) * 1024 + col] = acc[mt][nt][r] + bv;
    }
  }
}

// ---------------------------------------------------------------------------
extern "C" void kernel_launch(void* const* d_in, const int* in_sizes, int n_in,
                              void* d_out, int out_size, void* d_ws, size_t ws_size,
                              hipStream_t stream) {
  const float* x  = (const float*)d_in[0];
  const float* Wq = (const float*)d_in[1];
  const float* Wk = (const float*)d_in[2];
  const float* Wv = (const float*)d_in[3];
  const float* Wo = (const float*)d_in[4];
  const float* bo = (const float*)d_in[5];
  float* out = (float*)d_out;
  unsigned short* ws = (unsigned short*)d_ws;

  const size_t SZ = (size_t)MR * DD;         // 4096*1024

  // ws: [0] Q (ctx in-place)  [1] K  [2] Vt[b][h][d][t]  [3] Wb  [4] xb (opt)
  unsigned short* Qb  = ws;
  unsigned short* Kbf = ws + SZ;
  unsigned short* Vt  = ws + 2 * SZ;
  unsigned short* Wb  = ws + 3 * SZ;
  unsigned short* xb  = ws + 4 * SZ;

  const bool fast = ws_size >= 5 * SZ * sizeof(unsigned short);

  cvt_all<<<dim3(fast ? 4096 : 2048), 256, 0, stream>>>(Wq, Wk, Wv, Wo, x, Wb, xb);
  if (fast)
    gemm_qkv<true><<<dim3(32, 24), 256, 0, stream>>>(x, xb, Wb, Qb, Kbf, Vt);
  else
    gemm_qkv<false><<<dim3(32, 24), 256, 0, stream>>>(x, xb, Wb, Qb, Kbf, Vt);
  attn<<<dim3(2 * NH * 8), 256, 0, stream>>>(Qb, Kbf, Vt, Qb);
  gemm_out<<<dim3(32, 8), 256, 0, stream>>>(Qb, Wb + 3 * (size_t)DD * DD, bo, out);
}

// Round 12
// 198.995 us; speedup vs baseline: 1.0655x; 1.0655x over previous
//
#include <hip/hip_runtime.h>

// Problem constants
#define TT 2048
#define DD 1024
#define NH 16
#define DH 64
#define MR 4096            // B*T rows

typedef __attribute__((ext_vector_type(8))) short bf16x8;
typedef __attribute__((ext_vector_type(4))) short bf16x4;
typedef __attribute__((ext_vector_type(4))) float f32x4;
typedef __attribute__((ext_vector_type(2))) unsigned int u32x2;

__device__ __forceinline__ float bf2f(unsigned short u) {
  unsigned int x = ((unsigned int)u) << 16;
  return __builtin_bit_cast(float, x);
}
__device__ __forceinline__ unsigned short f2bf(float f) {
  unsigned int x = __builtin_bit_cast(unsigned int, f);
  x = (x + 0x7fffu + ((x >> 16) & 1u)) >> 16;
  return (unsigned short)x;
}
__device__ __forceinline__ unsigned int pack_bf2(float a, float b) {
#if __has_builtin(__builtin_amdgcn_cvt_pk_bf16_f32)
  typedef __attribute__((ext_vector_type(2))) __bf16 bf2_t;
  bf2_t v = __builtin_amdgcn_cvt_pk_bf16_f32(a, b);
  return __builtin_bit_cast(unsigned int, v);
#else
  return (unsigned int)f2bf(a) | ((unsigned int)f2bf(b) << 16);
#endif
}
__device__ __forceinline__ bf16x8 load8(const float* p) {
  bf16x8 r;
#pragma unroll
  for (int e = 0; e < 8; ++e) r[e] = (short)f2bf(p[e]);
  return r;
}

#if __has_builtin(__builtin_amdgcn_mfma_f32_16x16x16_bf16)
#define MFMA_K16(A, B, C) __builtin_amdgcn_mfma_f32_16x16x16_bf16(A, B, C, 0, 0, 0)
#else
#define MFMA_K16(A, B, C) __builtin_amdgcn_mfma_f32_16x16x16bf16_1k(A, B, C, 0, 0, 0)
#endif

// Async global->LDS 16B/lane; LDS base wave-uniform, HW adds lane*16.
__device__ __forceinline__ void stage16(const unsigned short* g,
                                        unsigned short* lbase, int lane) {
#if __has_builtin(__builtin_amdgcn_global_load_lds)
  __builtin_amdgcn_global_load_lds(
      (const __attribute__((address_space(1))) unsigned int*)g,
      (__attribute__((address_space(3))) unsigned int*)(lbase + lane * 8),
      16, 0, 0);
#else
  *(bf16x8*)(lbase + lane * 8) = *(const bf16x8*)g;
#endif
}

// ---------------------------------------------------------------------------
// Convert: Wb rows = [Wk; Wq; Wv; Wo] (reference Q/K swap!); blocks >= 2048
// additionally convert x -> xb (linear).
// ---------------------------------------------------------------------------
__global__ __launch_bounds__(256) void cvt_all(
    const float* __restrict__ Wq, const float* __restrict__ Wk,
    const float* __restrict__ Wv, const float* __restrict__ Wo,
    const float* __restrict__ x,
    unsigned short* __restrict__ Wb, unsigned short* __restrict__ xb)
{
  int c = blockIdx.x * 256 + threadIdx.x;     // chunk of 8 elems
  if (c < 524288) {
    int idx = c * 8, n = idx >> 10, col = idx & 1023;
    const float* src = (n < 1024) ? Wk + (size_t)n * 1024
                     : (n < 2048) ? Wq + (size_t)(n - 1024) * 1024
                     : (n < 3072) ? Wv + (size_t)(n - 2048) * 1024
                                  : Wo + (size_t)(n - 3072) * 1024;
    *(bf16x8*)&Wb[idx] = load8(src + col);
  } else {
    size_t idx = (size_t)(c - 524288) * 8;
    *(bf16x8*)&xb[idx] = load8(&x[idx]);
  }
}

// ---------------------------------------------------------------------------
// Fused QKV projection with XCD-affine block decode: xcd = blockIdx&7 owns
// bm-tiles {xcd, xcd+8, xcd+16, xcd+24} -> each 256KB x-tile is fetched by
// ONE XCD and reused from its private L2 across all 24 bn-tiles (was: every
// XCD streamed the whole 16MB x -> ~8x HBM over-fetch).
// ---------------------------------------------------------------------------
template <bool FAST>
__global__ __launch_bounds__(256) void gemm_qkv(
    const float* __restrict__ x, const unsigned short* __restrict__ xb,
    const unsigned short* __restrict__ Wb,
    unsigned short* __restrict__ Q, unsigned short* __restrict__ Kb,
    unsigned short* __restrict__ Vt)
{
  __shared__ unsigned short pool[8704];      // As(4096)+Bs(4096) | Tt(8704)
  unsigned short* As = pool;
  unsigned short* Bs = pool + 4096;

  const int tid = threadIdx.x, wave = tid >> 6, lane = tid & 63;
  const int lr = lane & 15, quad = lane >> 4;
  const int cblk = blockIdx.x;               // 0..767
  const int xcd = cblk & 7, kk = cblk >> 3;  // kk 0..95
  const int bm = (xcd + (kk / 24) * 8) * 128;
  const int bn = (kk % 24) * 128;
  const int wm = (wave >> 1) * 64, wn = (wave & 1) * 64;

  f32x4 acc[4][4] = {};

  for (int k0 = 0; k0 < 1024; k0 += 32) {
#pragma unroll
    for (int i = 0; i < 2; ++i) {
      int c = wave * 128 + i * 64 + lane;    // chunk 0..511
      int row = c >> 2, l8 = (c & 3) ^ ((row >> 1) & 3);
      stage16(&Wb[(size_t)(bn + row) * 1024 + k0 + l8 * 8],
              &Bs[(wave * 2 + i) * 512], lane);
      if constexpr (FAST)
        stage16(&xb[(size_t)(bm + row) * 1024 + k0 + l8 * 8],
                &As[(wave * 2 + i) * 512], lane);
    }
    if constexpr (!FAST) {
#pragma unroll
      for (int i = 0; i < 2; ++i) {
        int c = tid + i * 256;
        int row = c >> 2, l8 = c & 3, p8 = l8 ^ ((row >> 1) & 3);
        *(bf16x8*)&As[row * 32 + p8 * 8] =
            load8(&x[(size_t)(bm + row) * 1024 + k0 + l8 * 8]);
      }
    }
    __syncthreads();

    bf16x8 af[4], bf[4];
#pragma unroll
    for (int mt = 0; mt < 4; ++mt) {
      int row = wm + mt * 16 + lr;
      af[mt] = *(const bf16x8*)&As[row * 32 + (quad ^ ((row >> 1) & 3)) * 8];
    }
#pragma unroll
    for (int nt = 0; nt < 4; ++nt) {
      int row = wn + nt * 16 + lr;
      bf[nt] = *(const bf16x8*)&Bs[row * 32 + (quad ^ ((row >> 1) & 3)) * 8];
    }
#pragma unroll
    for (int mt = 0; mt < 4; ++mt)
#pragma unroll
      for (int nt = 0; nt < 4; ++nt)
        acc[mt][nt] = __builtin_amdgcn_mfma_f32_16x16x32_bf16(
            af[mt], bf[nt], acc[mt][nt], 0, 0, 0);
    __syncthreads();
  }

  if (bn < 2048) {
    unsigned short* Cp = (bn < 1024) ? Q : Kb;
    int coff = (bn < 1024) ? bn : bn - 1024;
#pragma unroll
    for (int nt = 0; nt < 4; ++nt) {
      int col = coff + wn + nt * 16 + lr;
#pragma unroll
      for (int mt = 0; mt < 4; ++mt) {
        int row = bm + wm + mt * 16 + quad * 4;
#pragma unroll
        for (int r = 0; r < 4; ++r)
          Cp[(size_t)(row + r) * 1024 + col] = f2bf(acc[mt][nt][r]);
      }
    }
  } else {
    const int b = bm >> 11, t0 = bm & 2047, d0 = bn - 2048;
    unsigned short* Tt = pool;               // [64][136]
#pragma unroll
    for (int hv = 0; hv < 2; ++hv) {
      __syncthreads();
      if ((wave & 1) == hv) {
#pragma unroll
        for (int nt = 0; nt < 4; ++nt)
#pragma unroll
          for (int mt = 0; mt < 4; ++mt)
#pragma unroll
            for (int r = 0; r < 4; ++r)
              Tt[(nt * 16 + lr) * 136 + wm + mt * 16 + quad * 4 + r] =
                  f2bf(acc[mt][nt][r]);
      }
      __syncthreads();
#pragma unroll
      for (int ch = 0; ch < 4; ++ch) {
        int cc = tid + ch * 256;
        int d64 = cc >> 4, t8 = cc & 15;
        int dg = d0 + hv * 64 + d64;
        int h = dg >> 6, d = dg & 63;
        bf16x8 v = *(const bf16x8*)&Tt[d64 * 136 + t8 * 8];
        *(bf16x8*)&Vt[(((size_t)(b * NH + h) * 64 + d) << 11) + t0 + t8 * 8] = v;
      }
    }
  }
}

// ---------------------------------------------------------------------------
// Flash attention (R10 verbatim — 68.8 µs known-good: Sᵀ formulation,
// complementary pairing, async swizzled staging, packed-bf16 P, MFMA-ones l).
// R11's dual-q-group variant regressed (1 wave/SIMD exposed all latency).
// ---------------------------------------------------------------------------
__global__ __launch_bounds__(256) void attn(
    const unsigned short* __restrict__ Q,
    const unsigned short* __restrict__ Kb,
    const unsigned short* __restrict__ Vt,
    unsigned short* __restrict__ ctx)
{
  __shared__ unsigned short Ks[128 * 64];    // [kseq][d]   8 chunks/row
  __shared__ unsigned short Vs[64 * 128];    // [d][t]     16 chunks/row

  const int tid = threadIdx.x, wave = tid >> 6, lane = tid & 63;
  const int lr = lane & 15, quad = lane >> 4;
  const int p = blockIdx.x & 15;
  const int h = (blockIdx.x >> 4) & 15;
  const int b = blockIdx.x >> 8;

  const size_t qkbase = ((size_t)b * TT) * 1024 + h * 64;
  const size_t vbase  = ((size_t)(b * NH + h) * 64) << 11;
  const float QS = 0.125f * 1.44269504f;     // scale * log2(e)

  bf16x4 ones;
#pragma unroll
  for (int e = 0; e < 4; ++e) ones[e] = (short)0x3F80;   // bf16 1.0

#pragma unroll
  for (int pass = 0; pass < 2; ++pass) {
    const int qt = pass ? p : (31 - p);
    const int qrow0 = qt * 64 + wave * 16;
    const int qrow  = qrow0 + lr;

    bf16x8 qf[2];
#pragma unroll
    for (int kb = 0; kb < 2; ++kb) {
      bf16x8 raw = *(const bf16x8*)&Q[qkbase + (size_t)(qrow0 + lr) * 1024 + kb * 32 + quad * 8];
#pragma unroll
      for (int e = 0; e < 8; ++e)
        qf[kb][e] = (short)f2bf(bf2f((unsigned short)raw[e]) * QS);
    }

    float m_i = -1e30f;
    f32x4 od[4] = {};
    f32x4 ol = {};
    const int jmax = qt >> 1;

    for (int j = 0; j <= jmax; ++j) {
#pragma unroll
      for (int i = 0; i < 4; ++i) {
        int ci = (wave * 4 + i) * 64 + lane;
        int row = ci >> 3, lc = (ci & 7) ^ (row & 7);
        stage16(&Kb[qkbase + (size_t)(j * 128 + row) * 1024 + lc * 8],
                &Ks[(wave * 4 + i) * 512], lane);
      }
#pragma unroll
      for (int i = 0; i < 4; ++i) {
        int ci = (wave * 4 + i) * 64 + lane;
        int d = ci >> 4, lc = (ci & 15) ^ (d & 15);
        stage16(&Vt[vbase + ((size_t)d << 11) + j * 128 + lc * 8],
                &Vs[(wave * 4 + i) * 512], lane);
      }
      __syncthreads();

      const bool diag = (j == jmax);
      const int nlim = (diag && !(qt & 1)) ? 4 : 8;

      f32x4 s[8];
#pragma unroll
      for (int nt = 0; nt < 8; ++nt)
        if (nt < nlim) {
          f32x4 a = {0.f, 0.f, 0.f, 0.f};
#pragma unroll
          for (int kb = 0; kb < 2; ++kb) {
            int pc = (kb * 4 + quad) ^ (lr & 7);
            bf16x8 kf = *(const bf16x8*)&Ks[(nt * 16 + lr) * 64 + pc * 8];
            a = __builtin_amdgcn_mfma_f32_16x16x32_bf16(kf, qf[kb], a, 0, 0, 0);
          }
          s[nt] = a;
        }

      if (diag) {
#pragma unroll
        for (int nt = 0; nt < 8; ++nt)
          if (nt < nlim)
#pragma unroll
            for (int r = 0; r < 4; ++r) {
              int kpos = j * 128 + nt * 16 + quad * 4 + r;
              if (kpos > qrow) s[nt][r] = -1e30f;
            }
      }

      float mloc = -1e30f;
#pragma unroll
      for (int nt = 0; nt < 8; ++nt)
        if (nt < nlim)
#pragma unroll
          for (int r = 0; r < 4; ++r) mloc = fmaxf(mloc, s[nt][r]);
      mloc = fmaxf(mloc, __shfl_xor(mloc, 16, 64));
      mloc = fmaxf(mloc, __shfl_xor(mloc, 32, 64));
      float mnew = fmaxf(m_i, mloc);
      float alpha = exp2f(m_i - mnew);
      m_i = mnew;

      bf16x4 pk[8];
#pragma unroll
      for (int nt = 0; nt < 8; ++nt)
        if (nt < nlim) {
          float p0 = exp2f(s[nt][0] - mnew), p1 = exp2f(s[nt][1] - mnew);
          float p2 = exp2f(s[nt][2] - mnew), p3 = exp2f(s[nt][3] - mnew);
          u32x2 u = {pack_bf2(p0, p1), pack_bf2(p2, p3)};
          pk[nt] = __builtin_bit_cast(bf16x4, u);
        }

      float am[4];
#pragma unroll
      for (int r = 0; r < 4; ++r) am[r] = __shfl(alpha, quad * 4 + r, 16);
#pragma unroll
      for (int dt = 0; dt < 4; ++dt)
#pragma unroll
        for (int r = 0; r < 4; ++r) od[dt][r] *= am[r];
#pragma unroll
      for (int r = 0; r < 4; ++r) ol[r] *= am[r];

#pragma unroll
      for (int nt = 0; nt < 8; ++nt)
        if (nt < nlim) {
#pragma unroll
          for (int dt = 0; dt < 4; ++dt) {
            int pc = (nt * 2 + (quad >> 1)) ^ lr;
            bf16x4 vf = *(const bf16x4*)&Vs[(dt * 16 + lr) * 128 + pc * 8 + (quad & 1) * 4];
            od[dt] = MFMA_K16(pk[nt], vf, od[dt]);
          }
          ol = MFMA_K16(pk[nt], ones, ol);
        }
      __syncthreads();
    }

#pragma unroll
    for (int dt = 0; dt < 4; ++dt) {
      int col = h * 64 + dt * 16 + lr;
#pragma unroll
      for (int r = 0; r < 4; ++r) {
        int row = qrow0 + quad * 4 + r;
        ctx[((size_t)b * TT + row) * 1024 + col] = f2bf(od[dt][r] / ol[r]);
      }
    }
  }
}

// ---------------------------------------------------------------------------
// Output projection with XCD-affine decode: xcd owns bm-tiles {xcd, xcd+8,
// xcd+16, xcd+24} -> ctx tile L2-resident per XCD across all 8 bn-tiles.
// ---------------------------------------------------------------------------
__global__ __launch_bounds__(256) void gemm_out(
    const unsigned short* __restrict__ A,
    const unsigned short* __restrict__ Bw,
    const float* __restrict__ bias,
    float* __restrict__ out)
{
  __shared__ unsigned short pool[8192];
  unsigned short* As = pool;
  unsigned short* Bs = pool + 4096;

  const int tid = threadIdx.x, wave = tid >> 6, lane = tid & 63;
  const int lr = lane & 15, quad = lane >> 4;
  const int cblk = blockIdx.x;               // 0..255
  const int xcd = cblk & 7, kk = cblk >> 3;  // kk 0..31
  const int bm = (xcd + (kk / 8) * 8) * 128;
  const int bn = (kk % 8) * 128;
  const int wm = (wave >> 1) * 64, wn = (wave & 1) * 64;

  f32x4 acc[4][4] = {};

  for (int k0 = 0; k0 < 1024; k0 += 32) {
#pragma unroll
    for (int i = 0; i < 2; ++i) {
      int c = wave * 128 + i * 64 + lane;
      int row = c >> 2, l8 = (c & 3) ^ ((row >> 1) & 3);
      stage16(&A[(size_t)(bm + row) * 1024 + k0 + l8 * 8],
              &As[(wave * 2 + i) * 512], lane);
      stage16(&Bw[(size_t)(bn + row) * 1024 + k0 + l8 * 8],
              &Bs[(wave * 2 + i) * 512], lane);
    }
    __syncthreads();

    bf16x8 af[4], bf[4];
#pragma unroll
    for (int mt = 0; mt < 4; ++mt) {
      int row = wm + mt * 16 + lr;
      af[mt] = *(const bf16x8*)&As[row * 32 + (quad ^ ((row >> 1) & 3)) * 8];
    }
#pragma unroll
    for (int nt = 0; nt < 4; ++nt) {
      int row = wn + nt * 16 + lr;
      bf[nt] = *(const bf16x8*)&Bs[row * 32 + (quad ^ ((row >> 1) & 3)) * 8];
    }
#pragma unroll
    for (int mt = 0; mt < 4; ++mt)
#pragma unroll
      for (int nt = 0; nt < 4; ++nt)
        acc[mt][nt] = __builtin_amdgcn_mfma_f32_16x16x32_bf16(
            af[mt], bf[nt], acc[mt][nt], 0, 0, 0);
    __syncthreads();
  }

#pragma unroll
  for (int nt = 0; nt < 4; ++nt) {
    int col = bn + wn + nt * 16 + lr;
    float bv = bias[col];
#pragma unroll
    for (int mt = 0; mt < 4; ++mt) {
      int row = bm + wm + mt * 16 + quad * 4;
#pragma unroll
      for (int r = 0; r < 4; ++r)
        out[(size_t)(row + r) * 1024 + col] = acc[mt][nt][r] + bv;
    }
  }
}

// ---------------------------------------------------------------------------
extern "C" void kernel_launch(void* const* d_in, const int* in_sizes, int n_in,
                              void* d_out, int out_size, void* d_ws, size_t ws_size,
                              hipStream_t stream) {
  const float* x  = (const float*)d_in[0];
  const float* Wq = (const float*)d_in[1];
  const float* Wk = (const float*)d_in[2];
  const float* Wv = (const float*)d_in[3];
  const float* Wo = (const float*)d_in[4];
  const float* bo = (const float*)d_in[5];
  float* out = (float*)d_out;
  unsigned short* ws = (unsigned short*)d_ws;

  const size_t SZ = (size_t)MR * DD;         // 4096*1024

  // ws: [0] Q (ctx in-place)  [1] K  [2] Vt[b][h][d][t]  [3] Wb  [4] xb (opt)
  unsigned short* Qb  = ws;
  unsigned short* Kbf = ws + SZ;
  unsigned short* Vt  = ws + 2 * SZ;
  unsigned short* Wb  = ws + 3 * SZ;
  unsigned short* xb  = ws + 4 * SZ;

  const bool fast = ws_size >= 5 * SZ * sizeof(unsigned short);

  cvt_all<<<dim3(fast ? 4096 : 2048), 256, 0, stream>>>(Wq, Wk, Wv, Wo, x, Wb, xb);
  if (fast)
    gemm_qkv<true><<<dim3(768), 256, 0, stream>>>(x, xb, Wb, Qb, Kbf, Vt);
  else
    gemm_qkv<false><<<dim3(768), 256, 0, stream>>>(x, xb, Wb, Qb, Kbf, Vt);
  attn<<<dim3(2 * NH * 16), 256, 0, stream>>>(Qb, Kbf, Vt, Qb);
  gemm_out<<<dim3(256), 256, 0, stream>>>(Qb, Wb + 3 * (size_t)DD * DD, bo, out);
}

// Round 13
// 195.896 us; speedup vs baseline: 1.0823x; 1.0158x over previous
//
#include <hip/hip_runtime.h>

// Problem constants
#define TT 2048
#define DD 1024
#define NH 16
#define DH 64
#define MR 4096            // B*T rows

typedef __attribute__((ext_vector_type(8))) short bf16x8;
typedef __attribute__((ext_vector_type(4))) short bf16x4;
typedef __attribute__((ext_vector_type(4))) float f32x4;
typedef __attribute__((ext_vector_type(2))) unsigned int u32x2;

__device__ __forceinline__ float bf2f(unsigned short u) {
  unsigned int x = ((unsigned int)u) << 16;
  return __builtin_bit_cast(float, x);
}
__device__ __forceinline__ unsigned short f2bf(float f) {
  unsigned int x = __builtin_bit_cast(unsigned int, f);
  x = (x + 0x7fffu + ((x >> 16) & 1u)) >> 16;
  return (unsigned short)x;
}
__device__ __forceinline__ unsigned int pack_bf2(float a, float b) {
#if __has_builtin(__builtin_amdgcn_cvt_pk_bf16_f32)
  typedef __attribute__((ext_vector_type(2))) __bf16 bf2_t;
  bf2_t v = __builtin_amdgcn_cvt_pk_bf16_f32(a, b);
  return __builtin_bit_cast(unsigned int, v);
#else
  return (unsigned int)f2bf(a) | ((unsigned int)f2bf(b) << 16);
#endif
}
__device__ __forceinline__ bf16x8 load8(const float* p) {
  bf16x8 r;
#pragma unroll
  for (int e = 0; e < 8; ++e) r[e] = (short)f2bf(p[e]);
  return r;
}

#if __has_builtin(__builtin_amdgcn_mfma_f32_16x16x16_bf16)
#define MFMA_K16(A, B, C) __builtin_amdgcn_mfma_f32_16x16x16_bf16(A, B, C, 0, 0, 0)
#else
#define MFMA_K16(A, B, C) __builtin_amdgcn_mfma_f32_16x16x16bf16_1k(A, B, C, 0, 0, 0)
#endif

// Async global->LDS 16B/lane; LDS base wave-uniform, HW adds lane*16.
__device__ __forceinline__ void stage16(const unsigned short* g,
                                        unsigned short* lbase, int lane) {
#if __has_builtin(__builtin_amdgcn_global_load_lds)
  __builtin_amdgcn_global_load_lds(
      (const __attribute__((address_space(1))) unsigned int*)g,
      (__attribute__((address_space(3))) unsigned int*)(lbase + lane * 8),
      16, 0, 0);
#else
  *(bf16x8*)(lbase + lane * 8) = *(const bf16x8*)g;
#endif
}

// ---------------------------------------------------------------------------
// Convert: Wb rows = [Wk; Wq; Wv; Wo] (reference Q/K swap!); blocks >= 2048
// additionally convert x -> xb (linear).
// ---------------------------------------------------------------------------
__global__ __launch_bounds__(256) void cvt_all(
    const float* __restrict__ Wq, const float* __restrict__ Wk,
    const float* __restrict__ Wv, const float* __restrict__ Wo,
    const float* __restrict__ x,
    unsigned short* __restrict__ Wb, unsigned short* __restrict__ xb)
{
  int c = blockIdx.x * 256 + threadIdx.x;     // chunk of 8 elems
  if (c < 524288) {
    int idx = c * 8, n = idx >> 10, col = idx & 1023;
    const float* src = (n < 1024) ? Wk + (size_t)n * 1024
                     : (n < 2048) ? Wq + (size_t)(n - 1024) * 1024
                     : (n < 3072) ? Wv + (size_t)(n - 2048) * 1024
                                  : Wo + (size_t)(n - 3072) * 1024;
    *(bf16x8*)&Wb[idx] = load8(src + col);
  } else {
    size_t idx = (size_t)(c - 524288) * 8;
    *(bf16x8*)&xb[idx] = load8(&x[idx]);
  }
}

// ---------------------------------------------------------------------------
// Fused QKV projection with XCD-affine block decode (unchanged from R12).
// ---------------------------------------------------------------------------
template <bool FAST>
__global__ __launch_bounds__(256) void gemm_qkv(
    const float* __restrict__ x, const unsigned short* __restrict__ xb,
    const unsigned short* __restrict__ Wb,
    unsigned short* __restrict__ Q, unsigned short* __restrict__ Kb,
    unsigned short* __restrict__ Vt)
{
  __shared__ unsigned short pool[8704];      // As(4096)+Bs(4096) | Tt(8704)
  unsigned short* As = pool;
  unsigned short* Bs = pool + 4096;

  const int tid = threadIdx.x, wave = tid >> 6, lane = tid & 63;
  const int lr = lane & 15, quad = lane >> 4;
  const int cblk = blockIdx.x;               // 0..767
  const int xcd = cblk & 7, kk = cblk >> 3;  // kk 0..95
  const int bm = (xcd + (kk / 24) * 8) * 128;
  const int bn = (kk % 24) * 128;
  const int wm = (wave >> 1) * 64, wn = (wave & 1) * 64;

  f32x4 acc[4][4] = {};

  for (int k0 = 0; k0 < 1024; k0 += 32) {
#pragma unroll
    for (int i = 0; i < 2; ++i) {
      int c = wave * 128 + i * 64 + lane;    // chunk 0..511
      int row = c >> 2, l8 = (c & 3) ^ ((row >> 1) & 3);
      stage16(&Wb[(size_t)(bn + row) * 1024 + k0 + l8 * 8],
              &Bs[(wave * 2 + i) * 512], lane);
      if constexpr (FAST)
        stage16(&xb[(size_t)(bm + row) * 1024 + k0 + l8 * 8],
                &As[(wave * 2 + i) * 512], lane);
    }
    if constexpr (!FAST) {
#pragma unroll
      for (int i = 0; i < 2; ++i) {
        int c = tid + i * 256;
        int row = c >> 2, l8 = c & 3, p8 = l8 ^ ((row >> 1) & 3);
        *(bf16x8*)&As[row * 32 + p8 * 8] =
            load8(&x[(size_t)(bm + row) * 1024 + k0 + l8 * 8]);
      }
    }
    __syncthreads();

    bf16x8 af[4], bf[4];
#pragma unroll
    for (int mt = 0; mt < 4; ++mt) {
      int row = wm + mt * 16 + lr;
      af[mt] = *(const bf16x8*)&As[row * 32 + (quad ^ ((row >> 1) & 3)) * 8];
    }
#pragma unroll
    for (int nt = 0; nt < 4; ++nt) {
      int row = wn + nt * 16 + lr;
      bf[nt] = *(const bf16x8*)&Bs[row * 32 + (quad ^ ((row >> 1) & 3)) * 8];
    }
#pragma unroll
    for (int mt = 0; mt < 4; ++mt)
#pragma unroll
      for (int nt = 0; nt < 4; ++nt)
        acc[mt][nt] = __builtin_amdgcn_mfma_f32_16x16x32_bf16(
            af[mt], bf[nt], acc[mt][nt], 0, 0, 0);
    __syncthreads();
  }

  if (bn < 2048) {
    unsigned short* Cp = (bn < 1024) ? Q : Kb;
    int coff = (bn < 1024) ? bn : bn - 1024;
#pragma unroll
    for (int nt = 0; nt < 4; ++nt) {
      int col = coff + wn + nt * 16 + lr;
#pragma unroll
      for (int mt = 0; mt < 4; ++mt) {
        int row = bm + wm + mt * 16 + quad * 4;
#pragma unroll
        for (int r = 0; r < 4; ++r)
          Cp[(size_t)(row + r) * 1024 + col] = f2bf(acc[mt][nt][r]);
      }
    }
  } else {
    const int b = bm >> 11, t0 = bm & 2047, d0 = bn - 2048;
    unsigned short* Tt = pool;               // [64][136]
#pragma unroll
    for (int hv = 0; hv < 2; ++hv) {
      __syncthreads();
      if ((wave & 1) == hv) {
#pragma unroll
        for (int nt = 0; nt < 4; ++nt)
#pragma unroll
          for (int mt = 0; mt < 4; ++mt)
#pragma unroll
            for (int r = 0; r < 4; ++r)
              Tt[(nt * 16 + lr) * 136 + wm + mt * 16 + quad * 4 + r] =
                  f2bf(acc[mt][nt][r]);
      }
      __syncthreads();
#pragma unroll
      for (int ch = 0; ch < 4; ++ch) {
        int cc = tid + ch * 256;
        int d64 = cc >> 4, t8 = cc & 15;
        int dg = d0 + hv * 64 + d64;
        int h = dg >> 6, d = dg & 63;
        bf16x8 v = *(const bf16x8*)&Tt[d64 * 136 + t8 * 8];
        *(bf16x8*)&Vt[(((size_t)(b * NH + h) * 64 + d) << 11) + t0 + t8 * 8] = v;
      }
    }
  }
}

// ---------------------------------------------------------------------------
// Flash attention v6: R10 structure + (a) double-buffered async staging
// (prefetch j+1 overlaps compute j -> barrier no longer exposes load
// latency) and (b) XCD-affine bh decode: bh = (blk&7)|((blk>>3)&3)<<3 puts
// only 4 (b,h) K/V sets (2MB) on each XCD -> L2-resident re-reads (FETCH
// was 100MB vs ~30 ideal; misses were HBM-latency class ~900cyc).
// Pairing p<->31-p keeps every block at exactly 17 iters (assignment-
// independent balance). 512 blocks, 2/CU, LDS 64KB.
// ---------------------------------------------------------------------------
__global__ __launch_bounds__(256) void attn(
    const unsigned short* __restrict__ Q,
    const unsigned short* __restrict__ Kb,
    const unsigned short* __restrict__ Vt,
    unsigned short* __restrict__ ctx)
{
  __shared__ unsigned short Ks[2 * 128 * 64];   // dbuf [kseq][d]
  __shared__ unsigned short Vs[2 * 64 * 128];   // dbuf [d][t]

  const int tid = threadIdx.x, wave = tid >> 6, lane = tid & 63;
  const int lr = lane & 15, quad = lane >> 4;
  const int p  = blockIdx.x >> 5;                               // 0..15
  const int bh = (blockIdx.x & 7) | (((blockIdx.x >> 3) & 3) << 3);
  const int h = bh & 15, b = bh >> 4;

  const size_t qkbase = ((size_t)b * TT) * 1024 + h * 64;
  const size_t vbase  = ((size_t)(b * NH + h) * 64) << 11;
  const float QS = 0.125f * 1.44269504f;     // scale * log2(e)

  bf16x4 ones;
#pragma unroll
  for (int e = 0; e < 4; ++e) ones[e] = (short)0x3F80;   // bf16 1.0

  auto stage_kv = [&](int j, int bf) {
#pragma unroll
    for (int i = 0; i < 4; ++i) {
      int ci = (wave * 4 + i) * 64 + lane;
      int row = ci >> 3, lc = (ci & 7) ^ (row & 7);
      stage16(&Kb[qkbase + (size_t)(j * 128 + row) * 1024 + lc * 8],
              &Ks[bf * 8192 + (wave * 4 + i) * 512], lane);
    }
#pragma unroll
    for (int i = 0; i < 4; ++i) {
      int ci = (wave * 4 + i) * 64 + lane;
      int d = ci >> 4, lc = (ci & 15) ^ (d & 15);
      stage16(&Vt[vbase + ((size_t)d << 11) + j * 128 + lc * 8],
              &Vs[bf * 8192 + (wave * 4 + i) * 512], lane);
    }
  };

#pragma unroll
  for (int pass = 0; pass < 2; ++pass) {
    const int qt = pass ? p : (31 - p);
    const int qrow0 = qt * 64 + wave * 16;
    const int qrow  = qrow0 + lr;

    bf16x8 qf[2];
#pragma unroll
    for (int kb = 0; kb < 2; ++kb) {
      bf16x8 raw = *(const bf16x8*)&Q[qkbase + (size_t)(qrow0 + lr) * 1024 + kb * 32 + quad * 8];
#pragma unroll
      for (int e = 0; e < 8; ++e)
        qf[kb][e] = (short)f2bf(bf2f((unsigned short)raw[e]) * QS);
    }

    float m_i = -1e30f;
    f32x4 od[4] = {};
    f32x4 ol = {};
    const int jmax = qt >> 1;

    stage_kv(0, 0);
    __syncthreads();

    for (int j = 0; j <= jmax; ++j) {
      const int buf = j & 1;
      const int boff = buf * 8192;
      if (j < jmax) stage_kv(j + 1, buf ^ 1);  // prefetch; lands by iter-end
                                               // barrier, overlapped w/ compute
      const bool diag = (j == jmax);
      const int nlim = (diag && !(qt & 1)) ? 4 : 8;

      f32x4 s[8];
#pragma unroll
      for (int nt = 0; nt < 8; ++nt)
        if (nt < nlim) {
          f32x4 a = {0.f, 0.f, 0.f, 0.f};
#pragma unroll
          for (int kb = 0; kb < 2; ++kb) {
            int pc = (kb * 4 + quad) ^ (lr & 7);
            bf16x8 kf = *(const bf16x8*)&Ks[boff + (nt * 16 + lr) * 64 + pc * 8];
            a = __builtin_amdgcn_mfma_f32_16x16x32_bf16(kf, qf[kb], a, 0, 0, 0);
          }
          s[nt] = a;
        }

      if (diag) {
#pragma unroll
        for (int nt = 0; nt < 8; ++nt)
          if (nt < nlim)
#pragma unroll
            for (int r = 0; r < 4; ++r) {
              int kpos = j * 128 + nt * 16 + quad * 4 + r;
              if (kpos > qrow) s[nt][r] = -1e30f;
            }
      }

      float mloc = -1e30f;
#pragma unroll
      for (int nt = 0; nt < 8; ++nt)
        if (nt < nlim)
#pragma unroll
          for (int r = 0; r < 4; ++r) mloc = fmaxf(mloc, s[nt][r]);
      mloc = fmaxf(mloc, __shfl_xor(mloc, 16, 64));
      mloc = fmaxf(mloc, __shfl_xor(mloc, 32, 64));
      float mnew = fmaxf(m_i, mloc);
      float alpha = exp2f(m_i - mnew);
      m_i = mnew;

      bf16x4 pk[8];
#pragma unroll
      for (int nt = 0; nt < 8; ++nt)
        if (nt < nlim) {
          float p0 = exp2f(s[nt][0] - mnew), p1 = exp2f(s[nt][1] - mnew);
          float p2 = exp2f(s[nt][2] - mnew), p3 = exp2f(s[nt][3] - mnew);
          u32x2 u = {pack_bf2(p0, p1), pack_bf2(p2, p3)};
          pk[nt] = __builtin_bit_cast(bf16x4, u);
        }

      float am[4];
#pragma unroll
      for (int r = 0; r < 4; ++r) am[r] = __shfl(alpha, quad * 4 + r, 16);
#pragma unroll
      for (int dt = 0; dt < 4; ++dt)
#pragma unroll
        for (int r = 0; r < 4; ++r) od[dt][r] *= am[r];
#pragma unroll
      for (int r = 0; r < 4; ++r) ol[r] *= am[r];

#pragma unroll
      for (int nt = 0; nt < 8; ++nt)
        if (nt < nlim) {
#pragma unroll
          for (int dt = 0; dt < 4; ++dt) {
            int pc = (nt * 2 + (quad >> 1)) ^ lr;
            bf16x4 vf = *(const bf16x4*)&Vs[boff + (dt * 16 + lr) * 128 + pc * 8 + (quad & 1) * 4];
            od[dt] = MFMA_K16(pk[nt], vf, od[dt]);
          }
          ol = MFMA_K16(pk[nt], ones, ol);
        }
      __syncthreads();   // reads of buf done; prefetch into buf^1 drained
    }

#pragma unroll
    for (int dt = 0; dt < 4; ++dt) {
      int col = h * 64 + dt * 16 + lr;
#pragma unroll
      for (int r = 0; r < 4; ++r) {
        int row = qrow0 + quad * 4 + r;
        ctx[((size_t)b * TT + row) * 1024 + col] = f2bf(od[dt][r] / ol[r]);
      }
    }
  }
}

// ---------------------------------------------------------------------------
// Output projection with XCD-affine decode (unchanged from R12).
// ---------------------------------------------------------------------------
__global__ __launch_bounds__(256) void gemm_out(
    const unsigned short* __restrict__ A,
    const unsigned short* __restrict__ Bw,
    const float* __restrict__ bias,
    float* __restrict__ out)
{
  __shared__ unsigned short pool[8192];
  unsigned short* As = pool;
  unsigned short* Bs = pool + 4096;

  const int tid = threadIdx.x, wave = tid >> 6, lane = tid & 63;
  const int lr = lane & 15, quad = lane >> 4;
  const int cblk = blockIdx.x;               // 0..255
  const int xcd = cblk & 7, kk = cblk >> 3;  // kk 0..31
  const int bm = (xcd + (kk / 8) * 8) * 128;
  const int bn = (kk % 8) * 128;
  const int wm = (wave >> 1) * 64, wn = (wave & 1) * 64;

  f32x4 acc[4][4] = {};

  for (int k0 = 0; k0 < 1024; k0 += 32) {
#pragma unroll
    for (int i = 0; i < 2; ++i) {
      int c = wave * 128 + i * 64 + lane;
      int row = c >> 2, l8 = (c & 3) ^ ((row >> 1) & 3);
      stage16(&A[(size_t)(bm + row) * 1024 + k0 + l8 * 8],
              &As[(wave * 2 + i) * 512], lane);
      stage16(&Bw[(size_t)(bn + row) * 1024 + k0 + l8 * 8],
              &Bs[(wave * 2 + i) * 512], lane);
    }
    __syncthreads();

    bf16x8 af[4], bf[4];
#pragma unroll
    for (int mt = 0; mt < 4; ++mt) {
      int row = wm + mt * 16 + lr;
      af[mt] = *(const bf16x8*)&As[row * 32 + (quad ^ ((row >> 1) & 3)) * 8];
    }
#pragma unroll
    for (int nt = 0; nt < 4; ++nt) {
      int row = wn + nt * 16 + lr;
      bf[nt] = *(const bf16x8*)&Bs[row * 32 + (quad ^ ((row >> 1) & 3)) * 8];
    }
#pragma unroll
    for (int mt = 0; mt < 4; ++mt)
#pragma unroll
      for (int nt = 0; nt < 4; ++nt)
        acc[mt][nt] = __builtin_amdgcn_mfma_f32_16x16x32_bf16(
            af[mt], bf[nt], acc[mt][nt], 0, 0, 0);
    __syncthreads();
  }

#pragma unroll
  for (int nt = 0; nt < 4; ++nt) {
    int col = bn + wn + nt * 16 + lr;
    float bv = bias[col];
#pragma unroll
    for (int mt = 0; mt < 4; ++mt) {
      int row = bm + wm + mt * 16 + quad * 4;
#pragma unroll
      for (int r = 0; r < 4; ++r)
        out[(size_t)(row + r) * 1024 + col] = acc[mt][nt][r] + bv;
    }
  }
}

// ---------------------------------------------------------------------------
extern "C" void kernel_launch(void* const* d_in, const int* in_sizes, int n_in,
                              void* d_out, int out_size, void* d_ws, size_t ws_size,
                              hipStream_t stream) {
  const float* x  = (const float*)d_in[0];
  const float* Wq = (const float*)d_in[1];
  const float* Wk = (const float*)d_in[2];
  const float* Wv = (const float*)d_in[3];
  const float* Wo = (const float*)d_in[4];
  const float* bo = (const float*)d_in[5];
  float* out = (float*)d_out;
  unsigned short* ws = (unsigned short*)d_ws;

  const size_t SZ = (size_t)MR * DD;         // 4096*1024

  // ws: [0] Q (ctx in-place)  [1] K  [2] Vt[b][h][d][t]  [3] Wb  [4] xb (opt)
  unsigned short* Qb  = ws;
  unsigned short* Kbf = ws + SZ;
  unsigned short* Vt  = ws + 2 * SZ;
  unsigned short* Wb  = ws + 3 * SZ;
  unsigned short* xb  = ws + 4 * SZ;

  const bool fast = ws_size >= 5 * SZ * sizeof(unsigned short);

  cvt_all<<<dim3(fast ? 4096 : 2048), 256, 0, stream>>>(Wq, Wk, Wv, Wo, x, Wb, xb);
  if (fast)
    gemm_qkv<true><<<dim3(768), 256, 0, stream>>>(x, xb, Wb, Qb, Kbf, Vt);
  else
    gemm_qkv<false><<<dim3(768), 256, 0, stream>>>(x, xb, Wb, Qb, Kbf, Vt);
  attn<<<dim3(2 * NH * 16), 256, 0, stream>>>(Qb, Kbf, Vt, Qb);
  gemm_out<<<dim3(256), 256, 0, stream>>>(Qb, Wb + 3 * (size_t)DD * DD, bo, out);
}

// Round 14
// 194.976 us; speedup vs baseline: 1.0874x; 1.0047x over previous
//
#include <hip/hip_runtime.h>

// Problem constants
#define TT 2048
#define DD 1024
#define NH 16
#define DH 64
#define MR 4096            // B*T rows

typedef __attribute__((ext_vector_type(8))) short bf16x8;
typedef __attribute__((ext_vector_type(4))) short bf16x4;
typedef __attribute__((ext_vector_type(4))) float f32x4;
typedef __attribute__((ext_vector_type(2))) unsigned int u32x2;

__device__ __forceinline__ float bf2f(unsigned short u) {
  unsigned int x = ((unsigned int)u) << 16;
  return __builtin_bit_cast(float, x);
}
__device__ __forceinline__ unsigned short f2bf(float f) {
  unsigned int x = __builtin_bit_cast(unsigned int, f);
  x = (x + 0x7fffu + ((x >> 16) & 1u)) >> 16;
  return (unsigned short)x;
}
__device__ __forceinline__ unsigned int pack_bf2(float a, float b) {
#if __has_builtin(__builtin_amdgcn_cvt_pk_bf16_f32)
  typedef __attribute__((ext_vector_type(2))) __bf16 bf2_t;
  bf2_t v = __builtin_amdgcn_cvt_pk_bf16_f32(a, b);
  return __builtin_bit_cast(unsigned int, v);
#else
  return (unsigned int)f2bf(a) | ((unsigned int)f2bf(b) << 16);
#endif
}
__device__ __forceinline__ bf16x8 load8(const float* p) {
  bf16x8 r;
#pragma unroll
  for (int e = 0; e < 8; ++e) r[e] = (short)f2bf(p[e]);
  return r;
}

#if __has_builtin(__builtin_amdgcn_mfma_f32_16x16x16_bf16)
#define MFMA_K16(A, B, C) __builtin_amdgcn_mfma_f32_16x16x16_bf16(A, B, C, 0, 0, 0)
#else
#define MFMA_K16(A, B, C) __builtin_amdgcn_mfma_f32_16x16x16bf16_1k(A, B, C, 0, 0, 0)
#endif

// Async global->LDS 16B/lane; LDS base wave-uniform, HW adds lane*16.
__device__ __forceinline__ void stage16(const unsigned short* g,
                                        unsigned short* lbase, int lane) {
#if __has_builtin(__builtin_amdgcn_global_load_lds)
  __builtin_amdgcn_global_load_lds(
      (const __attribute__((address_space(1))) unsigned int*)g,
      (__attribute__((address_space(3))) unsigned int*)(lbase + lane * 8),
      16, 0, 0);
#else
  *(bf16x8*)(lbase + lane * 8) = *(const bf16x8*)g;
#endif
}

// ---------------------------------------------------------------------------
// Convert: Wb rows = [Wk; Wq; Wv; Wo] (reference Q/K swap!); blocks >= 2048
// additionally convert x -> xb (linear).
// ---------------------------------------------------------------------------
__global__ __launch_bounds__(256) void cvt_all(
    const float* __restrict__ Wq, const float* __restrict__ Wk,
    const float* __restrict__ Wv, const float* __restrict__ Wo,
    const float* __restrict__ x,
    unsigned short* __restrict__ Wb, unsigned short* __restrict__ xb)
{
  int c = blockIdx.x * 256 + threadIdx.x;     // chunk of 8 elems
  if (c < 524288) {
    int idx = c * 8, n = idx >> 10, col = idx & 1023;
    const float* src = (n < 1024) ? Wk + (size_t)n * 1024
                     : (n < 2048) ? Wq + (size_t)(n - 1024) * 1024
                     : (n < 3072) ? Wv + (size_t)(n - 2048) * 1024
                                  : Wo + (size_t)(n - 3072) * 1024;
    *(bf16x8*)&Wb[idx] = load8(src + col);
  } else {
    size_t idx = (size_t)(c - 524288) * 8;
    *(bf16x8*)&xb[idx] = load8(&x[idx]);
  }
}

// ---------------------------------------------------------------------------
// Fused QKV projection with XCD-affine block decode (unchanged from R12).
// ---------------------------------------------------------------------------
template <bool FAST>
__global__ __launch_bounds__(256) void gemm_qkv(
    const float* __restrict__ x, const unsigned short* __restrict__ xb,
    const unsigned short* __restrict__ Wb,
    unsigned short* __restrict__ Q, unsigned short* __restrict__ Kb,
    unsigned short* __restrict__ Vt)
{
  __shared__ unsigned short pool[8704];      // As(4096)+Bs(4096) | Tt(8704)
  unsigned short* As = pool;
  unsigned short* Bs = pool + 4096;

  const int tid = threadIdx.x, wave = tid >> 6, lane = tid & 63;
  const int lr = lane & 15, quad = lane >> 4;
  const int cblk = blockIdx.x;               // 0..767
  const int xcd = cblk & 7, kk = cblk >> 3;  // kk 0..95
  const int bm = (xcd + (kk / 24) * 8) * 128;
  const int bn = (kk % 24) * 128;
  const int wm = (wave >> 1) * 64, wn = (wave & 1) * 64;

  f32x4 acc[4][4] = {};

  for (int k0 = 0; k0 < 1024; k0 += 32) {
#pragma unroll
    for (int i = 0; i < 2; ++i) {
      int c = wave * 128 + i * 64 + lane;    // chunk 0..511
      int row = c >> 2, l8 = (c & 3) ^ ((row >> 1) & 3);
      stage16(&Wb[(size_t)(bn + row) * 1024 + k0 + l8 * 8],
              &Bs[(wave * 2 + i) * 512], lane);
      if constexpr (FAST)
        stage16(&xb[(size_t)(bm + row) * 1024 + k0 + l8 * 8],
                &As[(wave * 2 + i) * 512], lane);
    }
    if constexpr (!FAST) {
#pragma unroll
      for (int i = 0; i < 2; ++i) {
        int c = tid + i * 256;
        int row = c >> 2, l8 = c & 3, p8 = l8 ^ ((row >> 1) & 3);
        *(bf16x8*)&As[row * 32 + p8 * 8] =
            load8(&x[(size_t)(bm + row) * 1024 + k0 + l8 * 8]);
      }
    }
    __syncthreads();

    bf16x8 af[4], bf[4];
#pragma unroll
    for (int mt = 0; mt < 4; ++mt) {
      int row = wm + mt * 16 + lr;
      af[mt] = *(const bf16x8*)&As[row * 32 + (quad ^ ((row >> 1) & 3)) * 8];
    }
#pragma unroll
    for (int nt = 0; nt < 4; ++nt) {
      int row = wn + nt * 16 + lr;
      bf[nt] = *(const bf16x8*)&Bs[row * 32 + (quad ^ ((row >> 1) & 3)) * 8];
    }
#pragma unroll
    for (int mt = 0; mt < 4; ++mt)
#pragma unroll
      for (int nt = 0; nt < 4; ++nt)
        acc[mt][nt] = __builtin_amdgcn_mfma_f32_16x16x32_bf16(
            af[mt], bf[nt], acc[mt][nt], 0, 0, 0);
    __syncthreads();
  }

  if (bn < 2048) {
    unsigned short* Cp = (bn < 1024) ? Q : Kb;
    int coff = (bn < 1024) ? bn : bn - 1024;
#pragma unroll
    for (int nt = 0; nt < 4; ++nt) {
      int col = coff + wn + nt * 16 + lr;
#pragma unroll
      for (int mt = 0; mt < 4; ++mt) {
        int row = bm + wm + mt * 16 + quad * 4;
#pragma unroll
        for (int r = 0; r < 4; ++r)
          Cp[(size_t)(row + r) * 1024 + col] = f2bf(acc[mt][nt][r]);
      }
    }
  } else {
    const int b = bm >> 11, t0 = bm & 2047, d0 = bn - 2048;
    unsigned short* Tt = pool;               // [64][136]
#pragma unroll
    for (int hv = 0; hv < 2; ++hv) {
      __syncthreads();
      if ((wave & 1) == hv) {
#pragma unroll
        for (int nt = 0; nt < 4; ++nt)
#pragma unroll
          for (int mt = 0; mt < 4; ++mt)
#pragma unroll
            for (int r = 0; r < 4; ++r)
              Tt[(nt * 16 + lr) * 136 + wm + mt * 16 + quad * 4 + r] =
                  f2bf(acc[mt][nt][r]);
      }
      __syncthreads();
#pragma unroll
      for (int ch = 0; ch < 4; ++ch) {
        int cc = tid + ch * 256;
        int d64 = cc >> 4, t8 = cc & 15;
        int dg = d0 + hv * 64 + d64;
        int h = dg >> 6, d = dg & 63;
        bf16x8 v = *(const bf16x8*)&Tt[d64 * 136 + t8 * 8];
        *(bf16x8*)&Vt[(((size_t)(b * NH + h) * 64 + d) << 11) + t0 + t8 * 8] = v;
      }
    }
  }
}

// ---------------------------------------------------------------------------
// Flash attention v7: R10's single-buffered loop (32KB LDS, 4 blocks/CU,
// stage -> barrier -> compute; cross-block overlap hides staging latency)
// + R13's XCD-affine bh decode (bh = (blk&7)|((blk>>3)&3)<<3): only 4 (b,h)
// K/V sets (2MB) per XCD -> L2-resident staging (R13 proved FETCH 100->12MB,
// conflicts->0). R13's dbuf is DROPPED: compiler inserts vmcnt(0) before
// ds_reads (can't prove LDS non-aliasing with in-flight glds) and 64KB LDS
// halves residency -> prefetch serialized, 69->93µs regression.
// Pairing p<->31-p keeps every block at exactly 17 j-iters.
// ---------------------------------------------------------------------------
__global__ __launch_bounds__(256) void attn(
    const unsigned short* __restrict__ Q,
    const unsigned short* __restrict__ Kb,
    const unsigned short* __restrict__ Vt,
    unsigned short* __restrict__ ctx)
{
  __shared__ unsigned short Ks[128 * 64];    // [kseq][d]   8 chunks/row
  __shared__ unsigned short Vs[64 * 128];    // [d][t]     16 chunks/row

  const int tid = threadIdx.x, wave = tid >> 6, lane = tid & 63;
  const int lr = lane & 15, quad = lane >> 4;
  const int p  = blockIdx.x >> 5;                               // 0..15
  const int bh = (blockIdx.x & 7) | (((blockIdx.x >> 3) & 3) << 3);
  const int h = bh & 15, b = bh >> 4;

  const size_t qkbase = ((size_t)b * TT) * 1024 + h * 64;
  const size_t vbase  = ((size_t)(b * NH + h) * 64) << 11;
  const float QS = 0.125f * 1.44269504f;     // scale * log2(e)

  bf16x4 ones;
#pragma unroll
  for (int e = 0; e < 4; ++e) ones[e] = (short)0x3F80;   // bf16 1.0

#pragma unroll
  for (int pass = 0; pass < 2; ++pass) {
    const int qt = pass ? p : (31 - p);
    const int qrow0 = qt * 64 + wave * 16;
    const int qrow  = qrow0 + lr;

    bf16x8 qf[2];
#pragma unroll
    for (int kb = 0; kb < 2; ++kb) {
      bf16x8 raw = *(const bf16x8*)&Q[qkbase + (size_t)(qrow0 + lr) * 1024 + kb * 32 + quad * 8];
#pragma unroll
      for (int e = 0; e < 8; ++e)
        qf[kb][e] = (short)f2bf(bf2f((unsigned short)raw[e]) * QS);
    }

    float m_i = -1e30f;
    f32x4 od[4] = {};
    f32x4 ol = {};
    const int jmax = qt >> 1;

    for (int j = 0; j <= jmax; ++j) {
#pragma unroll
      for (int i = 0; i < 4; ++i) {
        int ci = (wave * 4 + i) * 64 + lane;
        int row = ci >> 3, lc = (ci & 7) ^ (row & 7);
        stage16(&Kb[qkbase + (size_t)(j * 128 + row) * 1024 + lc * 8],
                &Ks[(wave * 4 + i) * 512], lane);
      }
#pragma unroll
      for (int i = 0; i < 4; ++i) {
        int ci = (wave * 4 + i) * 64 + lane;
        int d = ci >> 4, lc = (ci & 15) ^ (d & 15);
        stage16(&Vt[vbase + ((size_t)d << 11) + j * 128 + lc * 8],
                &Vs[(wave * 4 + i) * 512], lane);
      }
      __syncthreads();

      const bool diag = (j == jmax);
      const int nlim = (diag && !(qt & 1)) ? 4 : 8;

      f32x4 s[8];
#pragma unroll
      for (int nt = 0; nt < 8; ++nt)
        if (nt < nlim) {
          f32x4 a = {0.f, 0.f, 0.f, 0.f};
#pragma unroll
          for (int kb = 0; kb < 2; ++kb) {
            int pc = (kb * 4 + quad) ^ (lr & 7);
            bf16x8 kf = *(const bf16x8*)&Ks[(nt * 16 + lr) * 64 + pc * 8];
            a = __builtin_amdgcn_mfma_f32_16x16x32_bf16(kf, qf[kb], a, 0, 0, 0);
          }
          s[nt] = a;
        }

      if (diag) {
#pragma unroll
        for (int nt = 0; nt < 8; ++nt)
          if (nt < nlim)
#pragma unroll
            for (int r = 0; r < 4; ++r) {
              int kpos = j * 128 + nt * 16 + quad * 4 + r;
              if (kpos > qrow) s[nt][r] = -1e30f;
            }
      }

      float mloc = -1e30f;
#pragma unroll
      for (int nt = 0; nt < 8; ++nt)
        if (nt < nlim)
#pragma unroll
          for (int r = 0; r < 4; ++r) mloc = fmaxf(mloc, s[nt][r]);
      mloc = fmaxf(mloc, __shfl_xor(mloc, 16, 64));
      mloc = fmaxf(mloc, __shfl_xor(mloc, 32, 64));
      float mnew = fmaxf(m_i, mloc);
      float alpha = exp2f(m_i - mnew);
      m_i = mnew;

      bf16x4 pk[8];
#pragma unroll
      for (int nt = 0; nt < 8; ++nt)
        if (nt < nlim) {
          float p0 = exp2f(s[nt][0] - mnew), p1 = exp2f(s[nt][1] - mnew);
          float p2 = exp2f(s[nt][2] - mnew), p3 = exp2f(s[nt][3] - mnew);
          u32x2 u = {pack_bf2(p0, p1), pack_bf2(p2, p3)};
          pk[nt] = __builtin_bit_cast(bf16x4, u);
        }

      float am[4];
#pragma unroll
      for (int r = 0; r < 4; ++r) am[r] = __shfl(alpha, quad * 4 + r, 16);
#pragma unroll
      for (int dt = 0; dt < 4; ++dt)
#pragma unroll
        for (int r = 0; r < 4; ++r) od[dt][r] *= am[r];
#pragma unroll
      for (int r = 0; r < 4; ++r) ol[r] *= am[r];

#pragma unroll
      for (int nt = 0; nt < 8; ++nt)
        if (nt < nlim) {
#pragma unroll
          for (int dt = 0; dt < 4; ++dt) {
            int pc = (nt * 2 + (quad >> 1)) ^ lr;
            bf16x4 vf = *(const bf16x4*)&Vs[(dt * 16 + lr) * 128 + pc * 8 + (quad & 1) * 4];
            od[dt] = MFMA_K16(pk[nt], vf, od[dt]);
          }
          ol = MFMA_K16(pk[nt], ones, ol);
        }
      __syncthreads();
    }

#pragma unroll
    for (int dt = 0; dt < 4; ++dt) {
      int col = h * 64 + dt * 16 + lr;
#pragma unroll
      for (int r = 0; r < 4; ++r) {
        int row = qrow0 + quad * 4 + r;
        ctx[((size_t)b * TT + row) * 1024 + col] = f2bf(od[dt][r] / ol[r]);
      }
    }
  }
}

// ---------------------------------------------------------------------------
// Output projection with XCD-affine decode (unchanged from R12).
// ---------------------------------------------------------------------------
__global__ __launch_bounds__(256) void gemm_out(
    const unsigned short* __restrict__ A,
    const unsigned short* __restrict__ Bw,
    const float* __restrict__ bias,
    float* __restrict__ out)
{
  __shared__ unsigned short pool[8192];
  unsigned short* As = pool;
  unsigned short* Bs = pool + 4096;

  const int tid = threadIdx.x, wave = tid >> 6, lane = tid & 63;
  const int lr = lane & 15, quad = lane >> 4;
  const int cblk = blockIdx.x;               // 0..255
  const int xcd = cblk & 7, kk = cblk >> 3;  // kk 0..31
  const int bm = (xcd + (kk / 8) * 8) * 128;
  const int bn = (kk % 8) * 128;
  const int wm = (wave >> 1) * 64, wn = (wave & 1) * 64;

  f32x4 acc[4][4] = {};

  for (int k0 = 0; k0 < 1024; k0 += 32) {
#pragma unroll
    for (int i = 0; i < 2; ++i) {
      int c = wave * 128 + i * 64 + lane;
      int row = c >> 2, l8 = (c & 3) ^ ((row >> 1) & 3);
      stage16(&A[(size_t)(bm + row) * 1024 + k0 + l8 * 8],
              &As[(wave * 2 + i) * 512], lane);
      stage16(&Bw[(size_t)(bn + row) * 1024 + k0 + l8 * 8],
              &Bs[(wave * 2 + i) * 512], lane);
    }
    __syncthreads();

    bf16x8 af[4], bf[4];
#pragma unroll
    for (int mt = 0; mt < 4; ++mt) {
      int row = wm + mt * 16 + lr;
      af[mt] = *(const bf16x8*)&As[row * 32 + (quad ^ ((row >> 1) & 3)) * 8];
    }
#pragma unroll
    for (int nt = 0; nt < 4; ++nt) {
      int row = wn + nt * 16 + lr;
      bf[nt] = *(const bf16x8*)&Bs[row * 32 + (quad ^ ((row >> 1) & 3)) * 8];
    }
#pragma unroll
    for (int mt = 0; mt < 4; ++mt)
#pragma unroll
      for (int nt = 0; nt < 4; ++nt)
        acc[mt][nt] = __builtin_amdgcn_mfma_f32_16x16x32_bf16(
            af[mt], bf[nt], acc[mt][nt], 0, 0, 0);
    __syncthreads();
  }

#pragma unroll
  for (int nt = 0; nt < 4; ++nt) {
    int col = bn + wn + nt * 16 + lr;
    float bv = bias[col];
#pragma unroll
    for (int mt = 0; mt < 4; ++mt) {
      int row = bm + wm + mt * 16 + quad * 4;
#pragma unroll
      for (int r = 0; r < 4; ++r)
        out[(size_t)(row + r) * 1024 + col] = acc[mt][nt][r] + bv;
    }
  }
}

// ---------------------------------------------------------------------------
extern "C" void kernel_launch(void* const* d_in, const int* in_sizes, int n_in,
                              void* d_out, int out_size, void* d_ws, size_t ws_size,
                              hipStream_t stream) {
  const float* x  = (const float*)d_in[0];
  const float* Wq = (const float*)d_in[1];
  const float* Wk = (const float*)d_in[2];
  const float* Wv = (const float*)d_in[3];
  const float* Wo = (const float*)d_in[4];
  const float* bo = (const float*)d_in[5];
  float* out = (float*)d_out;
  unsigned short* ws = (unsigned short*)d_ws;

  const size_t SZ = (size_t)MR * DD;         // 4096*1024

  // ws: [0] Q (ctx in-place)  [1] K  [2] Vt[b][h][d][t]  [3] Wb  [4] xb (opt)
  unsigned short* Qb  = ws;
  unsigned short* Kbf = ws + SZ;
  unsigned short* Vt  = ws + 2 * SZ;
  unsigned short* Wb  = ws + 3 * SZ;
  unsigned short* xb  = ws + 4 * SZ;

  const bool fast = ws_size >= 5 * SZ * sizeof(unsigned short);

  cvt_all<<<dim3(fast ? 4096 : 2048), 256, 0, stream>>>(Wq, Wk, Wv, Wo, x, Wb, xb);
  if (fast)
    gemm_qkv<true><<<dim3(768), 256, 0, stream>>>(x, xb, Wb, Qb, Kbf, Vt);
  else
    gemm_qkv<false><<<dim3(768), 256, 0, stream>>>(x, xb, Wb, Qb, Kbf, Vt);
  attn<<<dim3(2 * NH * 16), 256, 0, stream>>>(Qb, Kbf, Vt, Qb);
  gemm_out<<<dim3(256), 256, 0, stream>>>(Qb, Wb + 3 * (size_t)DD * DD, bo, out);
}